// Round 1
// baseline (134.383 us; speedup 1.0000x reference)
//
#include <hip/hip_runtime.h>
#include <math.h>

// PRT order-3 spherical-harmonic projection.
// out[r][k] = clip( w * sum_s sh_k(theta[r][s], phi[r][s]) * vis[r][s], -2, 2 )
// w = 4*pi/(n*n). All 16 SH basis functions (l<=3) are expanded in closed
// form; normalization constants folded to compile-time scalars.
//
// One wave (64 lanes) per ray; each lane processes 4 samples via float4
// loads (fully coalesced, 16B/lane); butterfly shfl_xor reduction; lane 0
// writes the 16 outputs. Memory-bound: ~100.7 MB read -> ~16us floor.

static __device__ __forceinline__ float clampf(float v) {
    return fminf(fmaxf(v, -2.0f), 2.0f);
}

__global__ __launch_bounds__(256) void prt_kernel(
    const float* __restrict__ vis,
    const float* __restrict__ phi,
    const float* __restrict__ theta,
    const int* __restrict__ n_ptr,
    float* __restrict__ out,
    int n_rays)
{
    const int lane = threadIdx.x & 63;
    const int wave = threadIdx.x >> 6;
    const int ray  = blockIdx.x * 4 + wave;
    if (ray >= n_rays) return;

    const int base = ray * 256 + lane * 4;

    const float4 ph = *reinterpret_cast<const float4*>(phi + base);
    const float4 th = *reinterpret_cast<const float4*>(theta + base);
    const float4 vv = *reinterpret_cast<const float4*>(vis + base);

    const float* phs = reinterpret_cast<const float*>(&ph);
    const float* ths = reinterpret_cast<const float*>(&th);
    const float* vvs = reinterpret_cast<const float*>(&vv);

    // Monomial accumulators (indexed by final SH slot where possible):
    // 0: v        1: v*s*sp      2: v*x        3: v*s*cp
    // 4: v*s2q*sin2   5: v*x*s*sp  6: v*x^2     7: v*x*s*cp
    // 8: v*s2q*cos2   9: v*s^3*sin3  10: v*x*s^2*sin2  11: v*x^2*s*sp
    // 12: v*x^3   13: v*x^2*s*cp  14: v*x*s^2*cos2   15: v*s^3*cos3
    float acc[16];
    #pragma unroll
    for (int i = 0; i < 16; ++i) acc[i] = 0.0f;

    #pragma unroll
    for (int j = 0; j < 4; ++j) {
        const float x  = __cosf(ths[j]);
        const float sq = (1.0f + x) * (1.0f - x);   // sin^2(theta)
        const float s  = __fsqrt_rn(sq);            // sin(theta) >= 0
        float sp, cp;
        __sincosf(phs[j], &sp, &cp);
        const float s2 = 2.0f * sp * cp;            // sin(2phi)
        const float c2 = 1.0f - 2.0f * sp * sp;     // cos(2phi)
        const float s3 = s2 * cp + c2 * sp;         // sin(3phi)
        const float c3 = c2 * cp - s2 * sp;         // cos(3phi)

        const float v    = vvs[j];
        const float vx   = v * x;
        const float vx2  = vx * x;
        const float vx3  = vx2 * x;
        const float vsq  = v * sq;
        const float vxsq = vx * sq;
        const float vsqs = vsq * s;                 // v*sin^3
        const float t1   = v * s;
        const float t2   = vx * s;
        const float t3   = vx2 * s;

        acc[0]  += v;
        acc[1]  += t1 * sp;
        acc[2]  += vx;
        acc[3]  += t1 * cp;
        acc[4]  += vsq * s2;
        acc[5]  += t2 * sp;
        acc[6]  += vx2;
        acc[7]  += t2 * cp;
        acc[8]  += vsq * c2;
        acc[9]  += vsqs * s3;
        acc[10] += vxsq * s2;
        acc[11] += t3 * sp;
        acc[12] += vx3;
        acc[13] += t3 * cp;
        acc[14] += vxsq * c2;
        acc[15] += vsqs * c3;
    }

    // Wave-wide butterfly reduction: every lane ends with the ray totals.
    #pragma unroll
    for (int m = 1; m < 64; m <<= 1) {
        #pragma unroll
        for (int i = 0; i < 16; ++i)
            acc[i] += __shfl_xor(acc[i], m, 64);
    }

    if (lane == 0) {
        const int n = *n_ptr;
        const float w = 12.566370614359172f / (float)(n * n);  // 4*pi/n^2

        // SH normalization constants (order 3, Condon-Shortley folded in).
        const float K00 =  0.28209479f;   // sqrt(1/4pi)
        const float K10 =  0.48860251f;   // sqrt(3/4pi)
        const float A1  = -0.48860251f;   // -sqrt2*K11
        const float A2  =  0.54627422f;   // 3*sqrt2*K22 = sqrt(15/16pi)
        const float B1  = -1.09254843f;   // -3*sqrt2*K21
        const float K20 =  0.63078314f;   // sqrt(5/4pi)
        const float A3  = -0.59004360f;   // -15*sqrt2*K33
        const float B2  =  1.44530570f;   // 15*sqrt2*K32
        const float C1  = -0.45704579f;   // -1.5*sqrt2*K31
        const float K30 =  0.74635267f;   // sqrt(7/4pi)

        float o[16];
        o[0]  = K00 * acc[0];
        o[1]  = A1  * acc[1];
        o[2]  = K10 * acc[2];
        o[3]  = A1  * acc[3];
        o[4]  = A2  * acc[4];
        o[5]  = B1  * acc[5];
        o[6]  = K20 * (1.5f * acc[6] - 0.5f * acc[0]);
        o[7]  = B1  * acc[7];
        o[8]  = A2  * acc[8];
        o[9]  = A3  * acc[9];
        o[10] = B2  * acc[10];
        o[11] = C1  * (5.0f * acc[11] - acc[1]);
        o[12] = K30 * (2.5f * acc[12] - 1.5f * acc[2]);
        o[13] = C1  * (5.0f * acc[13] - acc[3]);
        o[14] = B2  * acc[14];
        o[15] = A3  * acc[15];

        float4* op = reinterpret_cast<float4*>(out + ray * 16);
        #pragma unroll
        for (int q = 0; q < 4; ++q) {
            float4 t;
            t.x = clampf(o[q * 4 + 0] * w);
            t.y = clampf(o[q * 4 + 1] * w);
            t.z = clampf(o[q * 4 + 2] * w);
            t.w = clampf(o[q * 4 + 3] * w);
            op[q] = t;
        }
    }
}

extern "C" void kernel_launch(void* const* d_in, const int* in_sizes, int n_in,
                              void* d_out, int out_size, void* d_ws, size_t ws_size,
                              hipStream_t stream) {
    const float* vis   = (const float*)d_in[0];   // p_vis [R,S,1]
    const float* phi   = (const float*)d_in[1];   // [R,S]
    const float* theta = (const float*)d_in[2];   // [R,S]
    const int*   n_ptr = (const int*)d_in[3];     // scalar n (=16)

    float* out = (float*)d_out;                   // [R,16] f32

    const int n_rays = in_sizes[1] / 256;         // S = n*n = 256
    const int blocks = (n_rays + 3) / 4;          // 4 waves (rays) per block
    prt_kernel<<<blocks, 256, 0, stream>>>(vis, phi, theta, n_ptr, out, n_rays);
}

// Round 2
// 119.863 us; speedup vs baseline: 1.1211x; 1.1211x over previous
//
#include <hip/hip_runtime.h>
#include <math.h>

// PRT order-3 SH projection: out[r][k] = clip(w * sum_s sh_k(th,ph)*vis, -2, 2)
// One wave per ray, 4 samples/lane via float4 loads (48B/lane, coalesced).
//
// Reduction: multi-value butterfly. Step mask=m halves the per-lane value
// count, partitioning coefficients by bit log2(m) to match the lane's bit.
// After masks 1,2,4,8 lane l holds coeff (l&15) summed over its 16-lane
// group; xor-16 + xor-32 finish. 17 shuffles total (vs 96 naive).
// l>=2 Legendre combos are folded into per-sample accumulation so each
// coefficient needs exactly one final constant.

__global__ __launch_bounds__(256) void prt_kernel(
    const float* __restrict__ vis,
    const float* __restrict__ phi,
    const float* __restrict__ theta,
    const int* __restrict__ n_ptr,
    float* __restrict__ out,
    int n_rays)
{
    const int lane = threadIdx.x & 63;
    const int wave = threadIdx.x >> 6;
    const int ray  = blockIdx.x * 4 + wave;
    if (ray >= n_rays) return;

    const int base = ray * 256 + lane * 4;

    const float4 ph = *reinterpret_cast<const float4*>(phi + base);
    const float4 th = *reinterpret_cast<const float4*>(theta + base);
    const float4 vv = *reinterpret_cast<const float4*>(vis + base);

    const float* phs = reinterpret_cast<const float*>(&ph);
    const float* ths = reinterpret_cast<const float*>(&th);
    const float* vvs = reinterpret_cast<const float*>(&vv);

    // acc[k] accumulates the k-th SH basis (sans normalization constant):
    // 0:1  1:s*sp  2:x  3:s*cp  4:s2q*sin2  5:xs*sp  6:(1.5x^2-.5)
    // 7:xs*cp  8:s2q*cos2  9:s^3*sin3  10:xs^2*sin2  11:s(5x^2-1)*sp
    // 12:x(2.5x^2-1.5)  13:s(5x^2-1)*cp  14:xs^2*cos2  15:s^3*cos3
    float acc[16];
    #pragma unroll
    for (int i = 0; i < 16; ++i) acc[i] = 0.0f;

    #pragma unroll
    for (int j = 0; j < 4; ++j) {
        float s, x;
        __sincosf(ths[j], &s, &x);          // theta in [0,pi] -> s >= 0
        float sp, cp;
        __sincosf(phs[j], &sp, &cp);

        const float sq = s * s;
        const float s2 = 2.0f * sp * cp;              // sin 2phi
        const float c2 = fmaf(-2.0f * sp, sp, 1.0f);  // cos 2phi
        const float s3 = fmaf(s2, cp, c2 * sp);       // sin 3phi
        const float c3 = fmaf(-s2, sp, c2 * cp);      // cos 3phi

        const float v    = vvs[j];
        const float t1   = v * s;
        const float vx   = v * x;
        const float t2   = vx * s;
        const float vsq  = v * sq;
        const float vxsq = vx * sq;
        const float vsqs = vsq * s;

        const float x2  = x * x;
        const float P20 = fmaf(1.5f, x2, -0.5f);
        const float q1  = fmaf(5.0f, x2, -1.0f);
        const float r30 = fmaf(2.5f, x2, -1.5f);
        const float t1q = t1 * q1;

        acc[0]  += v;
        acc[1]   = fmaf(t1,   sp,  acc[1]);
        acc[2]  += vx;
        acc[3]   = fmaf(t1,   cp,  acc[3]);
        acc[4]   = fmaf(vsq,  s2,  acc[4]);
        acc[5]   = fmaf(t2,   sp,  acc[5]);
        acc[6]   = fmaf(v,    P20, acc[6]);
        acc[7]   = fmaf(t2,   cp,  acc[7]);
        acc[8]   = fmaf(vsq,  c2,  acc[8]);
        acc[9]   = fmaf(vsqs, s3,  acc[9]);
        acc[10]  = fmaf(vxsq, s2,  acc[10]);
        acc[11]  = fmaf(t1q,  sp,  acc[11]);
        acc[12]  = fmaf(vx,   r30, acc[12]);
        acc[13]  = fmaf(t1q,  cp,  acc[13]);
        acc[14]  = fmaf(vxsq, c2,  acc[14]);
        acc[15]  = fmaf(vsqs, c3,  acc[15]);
    }

    // ---- multi-value butterfly reduction ----
    const bool b0 = (lane & 1) != 0;
    const bool b1 = (lane & 2) != 0;
    const bool b2 = (lane & 4) != 0;
    const bool b3 = (lane & 8) != 0;

    // mask=1: 16 -> 8 values; acc[j] = coeff(2j + b0)
    #pragma unroll
    for (int j = 0; j < 8; ++j) {
        const float a0 = acc[2 * j], a1 = acc[2 * j + 1];
        const float keep = b0 ? a1 : a0;
        const float give = b0 ? a0 : a1;
        acc[j] = keep + __shfl_xor(give, 1, 64);
    }
    // mask=2: 8 -> 4; acc[j] = coeff(4j + 2b1 + b0)
    #pragma unroll
    for (int j = 0; j < 4; ++j) {
        const float a0 = acc[2 * j], a1 = acc[2 * j + 1];
        const float keep = b1 ? a1 : a0;
        const float give = b1 ? a0 : a1;
        acc[j] = keep + __shfl_xor(give, 2, 64);
    }
    // mask=4: 4 -> 2
    #pragma unroll
    for (int j = 0; j < 2; ++j) {
        const float a0 = acc[2 * j], a1 = acc[2 * j + 1];
        const float keep = b2 ? a1 : a0;
        const float give = b2 ? a0 : a1;
        acc[j] = keep + __shfl_xor(give, 4, 64);
    }
    // mask=8: 2 -> 1; r = coeff(lane & 15) over 16-lane group
    float r;
    {
        const float keep = b3 ? acc[1] : acc[0];
        const float give = b3 ? acc[0] : acc[1];
        r = keep + __shfl_xor(give, 8, 64);
    }
    r += __shfl_xor(r, 16, 64);
    r += __shfl_xor(r, 32, 64);

    // ---- per-lane constant (coeff k = lane & 15), 15-select tree ----
    const float k01   = b0 ? -0.48860253f : 0.28209481f;
    const float k23   = b0 ? -0.48860253f : 0.48860253f;
    const float k45   = b0 ? -1.09254847f : 0.54627424f;
    const float k67   = b0 ? -1.09254847f : 0.63078316f;
    const float k89   = b0 ? -0.59004360f : 0.54627424f;
    const float k1011 = b0 ? -0.45704580f : 1.44530571f;
    const float k1213 = b0 ? -0.45704580f : 0.74635269f;
    const float k1415 = b0 ? -0.59004360f : 1.44530571f;
    const float ka = b1 ? k23 : k01;
    const float kb = b1 ? k67 : k45;
    const float kc = b1 ? k1011 : k89;
    const float kd = b1 ? k1415 : k1213;
    const float ke = b2 ? kb : ka;
    const float kf = b2 ? kd : kc;
    const float K  = b3 ? kf : ke;

    const int n = *n_ptr;
    const float w = 12.566370614359172f / (float)(n * n);  // 4*pi/n^2 (true pi)

    const float res = fminf(fmaxf(r * K * w, -2.0f), 2.0f);

    if (lane < 16)
        out[ray * 16 + lane] = res;
}

extern "C" void kernel_launch(void* const* d_in, const int* in_sizes, int n_in,
                              void* d_out, int out_size, void* d_ws, size_t ws_size,
                              hipStream_t stream) {
    const float* vis   = (const float*)d_in[0];   // p_vis [R,S,1]
    const float* phi   = (const float*)d_in[1];   // [R,S]
    const float* theta = (const float*)d_in[2];   // [R,S]
    const int*   n_ptr = (const int*)d_in[3];     // scalar n (=16)

    float* out = (float*)d_out;                   // [R,16] f32

    const int n_rays = in_sizes[1] / 256;         // S = n*n = 256
    const int blocks = (n_rays + 3) / 4;          // 4 rays (waves) per block
    prt_kernel<<<blocks, 256, 0, stream>>>(vis, phi, theta, n_ptr, out, n_rays);
}

// Round 10
// 119.341 us; speedup vs baseline: 1.1260x; 1.0044x over previous
//
#include <hip/hip_runtime.h>
#include <math.h>

// PRT order-3 SH projection: out[r][k] = clip(w * sum_s sh_k(th,ph)*vis, -2, 2)
//
// 4 rays per wave: lane l = (group g = l>>4 -> ray, slot t = l&15).
// Each lane loads 16 samples of its ray as 4x float4 per array (12 loads,
// 192 B/lane, all issued upfront for MLP). Multi-value butterfly over the
// 16-lane group (masks 1,2,4,8; 15 shuffles for 4 rays) leaves lane l with
// coefficient (l&15) of ray g; store is one coalesced 256 B per wave.
// l>=2 Legendre combos folded into accumulation so each coefficient needs
// exactly one final constant (15-cndmask select tree).
//
// (Seventh resubmission — rounds 3-9 all hit GPUAcquisitionTimeout; this
// kernel has not yet been benched.)

__global__ __launch_bounds__(256) void prt_kernel(
    const float* __restrict__ vis,
    const float* __restrict__ phi,
    const float* __restrict__ theta,
    const int* __restrict__ n_ptr,
    float* __restrict__ out,
    int n_rays)
{
    const int lane = threadIdx.x & 63;
    const int gwv  = (blockIdx.x * 256 + threadIdx.x) >> 6;  // global wave id
    const int ray0 = gwv * 4;
    if (ray0 >= n_rays) return;

    const int g = lane >> 4;       // ray within wave
    const int t = lane & 15;       // slot within 16-lane group
    const int sbase = (ray0 + g) * 256 + t * 4;

    // All 12 loads issued before any compute (max memory-level parallelism).
    float4 ph[4], th[4], vv[4];
    #pragma unroll
    for (int j = 0; j < 4; ++j) {
        const int a = sbase + 64 * j;
        ph[j] = *reinterpret_cast<const float4*>(phi + a);
        th[j] = *reinterpret_cast<const float4*>(theta + a);
        vv[j] = *reinterpret_cast<const float4*>(vis + a);
    }

    // acc[k], k-th SH basis sans constant:
    // 0:1  1:s*sp  2:x  3:s*cp  4:s^2*sin2  5:xs*sp  6:(1.5x^2-.5)
    // 7:xs*cp  8:s^2*cos2  9:s^3*sin3  10:xs^2*sin2  11:s(5x^2-1)*sp
    // 12:x(2.5x^2-1.5)  13:s(5x^2-1)*cp  14:xs^2*cos2  15:s^3*cos3
    float acc[16];
    #pragma unroll
    for (int i = 0; i < 16; ++i) acc[i] = 0.0f;

    #pragma unroll
    for (int j = 0; j < 4; ++j) {
        const float* phs = reinterpret_cast<const float*>(&ph[j]);
        const float* ths = reinterpret_cast<const float*>(&th[j]);
        const float* vvs = reinterpret_cast<const float*>(&vv[j]);
        #pragma unroll
        for (int e = 0; e < 4; ++e) {
            float s, x;
            __sincosf(ths[e], &s, &x);          // theta in [0,pi] -> s >= 0
            float sp, cp;
            __sincosf(phs[e], &sp, &cp);

            const float sq = s * s;
            const float s2 = 2.0f * sp * cp;              // sin 2phi
            const float c2 = fmaf(-2.0f * sp, sp, 1.0f);  // cos 2phi
            const float s3 = fmaf(s2, cp, c2 * sp);       // sin 3phi
            const float c3 = fmaf(-s2, sp, c2 * cp);      // cos 3phi

            const float v    = vvs[e];
            const float t1   = v * s;
            const float vx   = v * x;
            const float t2   = vx * s;
            const float vsq  = v * sq;
            const float vxsq = vx * sq;
            const float vsqs = vsq * s;

            const float x2  = x * x;
            const float P20 = fmaf(1.5f, x2, -0.5f);
            const float q1  = fmaf(5.0f, x2, -1.0f);
            const float r30 = fmaf(2.5f, x2, -1.5f);
            const float t1q = t1 * q1;

            acc[0]  += v;
            acc[1]   = fmaf(t1,   sp,  acc[1]);
            acc[2]  += vx;
            acc[3]   = fmaf(t1,   cp,  acc[3]);
            acc[4]   = fmaf(vsq,  s2,  acc[4]);
            acc[5]   = fmaf(t2,   sp,  acc[5]);
            acc[6]   = fmaf(v,    P20, acc[6]);
            acc[7]   = fmaf(t2,   cp,  acc[7]);
            acc[8]   = fmaf(vsq,  c2,  acc[8]);
            acc[9]   = fmaf(vsqs, s3,  acc[9]);
            acc[10]  = fmaf(vxsq, s2,  acc[10]);
            acc[11]  = fmaf(t1q,  sp,  acc[11]);
            acc[12]  = fmaf(vx,   r30, acc[12]);
            acc[13]  = fmaf(t1q,  cp,  acc[13]);
            acc[14]  = fmaf(vxsq, c2,  acc[14]);
            acc[15]  = fmaf(vsqs, c3,  acc[15]);
        }
    }

    // ---- multi-value butterfly within each 16-lane group ----
    const bool b0 = (lane & 1) != 0;
    const bool b1 = (lane & 2) != 0;
    const bool b2 = (lane & 4) != 0;
    const bool b3 = (lane & 8) != 0;

    // mask=1: 16 -> 8 values; acc[j] = coeff(2j + b0)
    #pragma unroll
    for (int j = 0; j < 8; ++j) {
        const float a0 = acc[2 * j], a1 = acc[2 * j + 1];
        const float keep = b0 ? a1 : a0;
        const float give = b0 ? a0 : a1;
        acc[j] = keep + __shfl_xor(give, 1, 64);
    }
    // mask=2: 8 -> 4; acc[j] = coeff(4j + 2b1 + b0)
    #pragma unroll
    for (int j = 0; j < 4; ++j) {
        const float a0 = acc[2 * j], a1 = acc[2 * j + 1];
        const float keep = b1 ? a1 : a0;
        const float give = b1 ? a0 : a1;
        acc[j] = keep + __shfl_xor(give, 2, 64);
    }
    // mask=4: 4 -> 2
    #pragma unroll
    for (int j = 0; j < 2; ++j) {
        const float a0 = acc[2 * j], a1 = acc[2 * j + 1];
        const float keep = b2 ? a1 : a0;
        const float give = b2 ? a0 : a1;
        acc[j] = keep + __shfl_xor(give, 4, 64);
    }
    // mask=8: 2 -> 1; r = coeff(lane & 15) for ray g, complete.
    float r;
    {
        const float keep = b3 ? acc[1] : acc[0];
        const float give = b3 ? acc[0] : acc[1];
        r = keep + __shfl_xor(give, 8, 64);
    }

    // ---- per-lane constant (coeff k = lane & 15), 15-select tree ----
    const float k01   = b0 ? -0.48860253f : 0.28209481f;
    const float k23   = b0 ? -0.48860253f : 0.48860253f;
    const float k45   = b0 ? -1.09254847f : 0.54627424f;
    const float k67   = b0 ? -1.09254847f : 0.63078316f;
    const float k89   = b0 ? -0.59004360f : 0.54627424f;
    const float k1011 = b0 ? -0.45704580f : 1.44530571f;
    const float k1213 = b0 ? -0.45704580f : 0.74635269f;
    const float k1415 = b0 ? -0.59004360f : 1.44530571f;
    const float ka = b1 ? k23 : k01;
    const float kb = b1 ? k67 : k45;
    const float kc = b1 ? k1011 : k89;
    const float kd = b1 ? k1415 : k1213;
    const float ke = b2 ? kb : ka;
    const float kf = b2 ? kd : kc;
    const float K  = b3 ? kf : ke;

    const int n = *n_ptr;
    const float w = 12.566370614359172f / (float)(n * n);  // 4*pi/n^2

    const float res = fminf(fmaxf(r * K * w, -2.0f), 2.0f);

    // lane l -> out[(ray0+g)*16 + t] = out[ray0*16 + l]: coalesced 256 B/wave
    out[ray0 * 16 + lane] = res;
}

extern "C" void kernel_launch(void* const* d_in, const int* in_sizes, int n_in,
                              void* d_out, int out_size, void* d_ws, size_t ws_size,
                              hipStream_t stream) {
    const float* vis   = (const float*)d_in[0];   // p_vis [R,S,1]
    const float* phi   = (const float*)d_in[1];   // [R,S]
    const float* theta = (const float*)d_in[2];   // [R,S]
    const int*   n_ptr = (const int*)d_in[3];     // scalar n (=16)

    float* out = (float*)d_out;                   // [R,16] f32

    const int n_rays = in_sizes[1] / 256;         // S = n*n = 256
    const int rays_per_block = 16;                // 4 waves x 4 rays
    const int blocks = (n_rays + rays_per_block - 1) / rays_per_block;
    prt_kernel<<<blocks, 256, 0, stream>>>(vis, phi, theta, n_ptr, out, n_rays);
}